// Round 6
// baseline (331.915 us; speedup 1.0000x reference)
//
#include <hip/hip_runtime.h>

#define DCH 128
#define T_EDGE 4096
#define B_MAX 512

typedef short bf16x8 __attribute__((ext_vector_type(8)));
typedef float f32x4 __attribute__((ext_vector_type(4)));

__device__ inline unsigned short f2bf(float f) {
    unsigned int u = __float_as_uint(f);
    unsigned int r = (u + 0x7fffu + ((u >> 16) & 1u)) >> 16;
    return (unsigned short)r;
}

__device__ inline void gload_lds16(const void* g, void* l) {
    __builtin_amdgcn_global_load_lds(
        (const __attribute__((address_space(1))) void*)g,
        (__attribute__((address_space(3))) void*)l, 16, 0, 0);
}

// -------- launch 1: per-node degree hist (global atomics, cnt is L2-resident)
//          + per-block LDS pre-hist -> gcount bucket sums
//          + Wf pack (4 trailing blocks; consumed 2 launches later)
__global__ __launch_bounds__(512) void k_hist(const int* __restrict__ col,
                                              int* __restrict__ cnt,
                                              int* __restrict__ gcount,
                                              const float* __restrict__ W,
                                              unsigned short* __restrict__ Wf,
                                              int E, int B, int nEB) {
    int tid = threadIdx.x;
    int wv = tid >> 6, lane = tid & 63;

    if (blockIdx.x >= nEB) {
        // Wf pack: frag (nt,ks): lane holds B[k=ks*32+(lane>>4)*8+j][n=nt*16+(lane&15)]
        int frag = (blockIdx.x - nEB) * 8 + wv;
        if (frag < 32) {
            int nt = frag >> 2, ks = frag & 3;
            int nn = nt * 16 + (lane & 15);
            int k0 = ks * 32 + ((lane >> 4) * 8);
            unsigned short tmp[8];
#pragma unroll
            for (int j = 0; j < 8; ++j) tmp[j] = f2bf(W[(size_t)(k0 + j) * DCH + nn]);
            *(uint4*)&Wf[((size_t)frag * 64 + lane) * 8] = *(const uint4*)tmp;
        }
        return;
    }

    __shared__ int bh[B_MAX];
    bh[tid] = 0;
    __syncthreads();

    int base_e = blockIdx.x * T_EDGE;
#pragma unroll
    for (int i = 0; i < 8; ++i) {
        int e = base_e + tid + i * 512;
        if (e < E) {
            int c = col[e];
            atomicAdd(&cnt[c], 1);          // per-node degree (400 KB, L2-hot)
            atomicAdd(&bh[c >> 8], 1);      // per-block bucket hist (LDS)
        }
    }
    __syncthreads();
    if (tid < B && bh[tid] > 0) atomicAdd(&gcount[tid], bh[tid]);
}

// -------- launch 2: per-bucket offsets: bbase = sum gcount[0..b), block-scan
//          of 256 node counts -> off / cur / dinv. (csr's proven patterns.)
__global__ __launch_bounds__(512) void k_off(const int* __restrict__ cnt,
                                             const int* __restrict__ gcount,
                                             int* __restrict__ off,
                                             int* __restrict__ cur,
                                             float* __restrict__ dinvf,
                                             int n, int B) {
    __shared__ int red1[8], red2[4];
    __shared__ int bbase_s;

    int b = blockIdx.x;
    int tid = threadIdx.x;
    int wv = tid >> 6, lane = tid & 63;

    int part = 0;
    for (int i = tid; i < b; i += 512) part += gcount[i];
#pragma unroll
    for (int o = 1; o < 64; o <<= 1) part += __shfl_xor(part, o, 64);
    if (lane == 0) red1[wv] = part;
    __syncthreads();
    if (tid == 0) {
        int s = 0;
        for (int w = 0; w < 8; ++w) s += red1[w];
        bbase_s = s;
    }
    __syncthreads();

    int x2 = 0, v = 0;
    if (tid < 256) {
        int node = (b << 8) + tid;
        v = (node < n) ? cnt[node] : 0;
        x2 = v;
#pragma unroll
        for (int o = 1; o < 64; o <<= 1) {
            int t = __shfl_up(x2, o, 64);
            if (lane >= o) x2 += t;
        }
        if (lane == 63) red2[wv] = x2;
    }
    __syncthreads();
    if (tid < 256) {
        int add = 0;
        for (int w = 0; w < wv; ++w) add += red2[w];
        int excl = x2 - v + add;
        int node = (b << 8) + tid;
        if (node < n) {
            int o2 = bbase_s + excl;
            off[node] = o2;
            cur[node] = o2;
            dinvf[node] = rsqrtf((float)(v + 1));
        }
    }
}

// -------- launch 3: scatter (blocks < nEB) || gemm (blocks >= nEB) ----------
// Scatter: slot = atomicAdd(&cur[col]) (L2 atomic-return, 8 independent in
// flight per thread), srow[slot] = row. Gemm: y = bf16(x @ W), 64 rows/block
// (= exactly the 32 KB LDS), verified R5 structure.
__global__ __launch_bounds__(512) void k_scat(const int* __restrict__ row,
                                              const int* __restrict__ col,
                                              int* __restrict__ cur,
                                              int* __restrict__ srow,
                                              const float* __restrict__ x,
                                              const unsigned short* __restrict__ Wf,
                                              unsigned short* __restrict__ y,
                                              int E, int n, int nEB) {
    __shared__ uint4 smem4[2048];               // 32 KB (gemm branch only)
    char* smem = (char*)smem4;

    int tid = threadIdx.x;
    int wv = tid >> 6, lane = tid & 63;

    if (blockIdx.x < nEB) {
        int base_e = blockIdx.x * T_EDGE;
        int er[8], ec[8];
#pragma unroll
        for (int i = 0; i < 8; ++i) {
            int e = base_e + tid + i * 512;
            er[i] = (e < E) ? row[e] : -1;
            ec[i] = (e < E) ? col[e] : 0;
        }
        int sl[8];
#pragma unroll
        for (int i = 0; i < 8; ++i)
            sl[i] = (er[i] >= 0) ? atomicAdd(&cur[ec[i]], 1) : 0;
#pragma unroll
        for (int i = 0; i < 8; ++i)
            if (er[i] >= 0) srow[sl[i]] = er[i];
    } else {
        // ---------------- gemm: y = bf16(x @ W), 64 rows/block ---------------
        int blockRow = (blockIdx.x - nEB) * 64;

#pragma unroll
        for (int t = 0; t < 4; ++t) {
            int off2 = t * 8192 + wv * 1024 + lane * 16;
            int r = off2 >> 9;                            // tile row 0..63
            int gr = blockRow + r;
            if (gr >= n) gr = n - 1;
            int colb = (off2 & 511) ^ ((r & 7) << 4);     // pre-swizzled source
            const char* src = (const char*)x + (size_t)gr * 512 + colb;
            char* dst = smem + t * 8192 + wv * 1024;
            gload_lds16(src, dst);
        }
        __syncthreads();

        f32x4 acc[4];
        f32x4 zero = {0.f, 0.f, 0.f, 0.f};
#pragma unroll
        for (int t = 0; t < 4; ++t) acc[t] = zero;

        const bf16x8* wfv = (const bf16x8*)Wf;
        int rowL = (wv >> 1) * 16 + (lane & 15);   // row-tile shared by 2 waves
        int ntBase = (wv & 1) * 4;                 // column-half split
        int q = lane >> 4;
        int swz = (rowL & 7) << 4;
#pragma unroll
        for (int ks = 0; ks < 4; ++ks) {
            int colb = ks * 128 + q * 32;
            float4 lo = *(const float4*)&smem[(rowL * 512 + colb) ^ swz];
            float4 hi = *(const float4*)&smem[(rowL * 512 + colb + 16) ^ swz];
            bf16x8 a;
            a[0] = (short)f2bf(lo.x); a[1] = (short)f2bf(lo.y);
            a[2] = (short)f2bf(lo.z); a[3] = (short)f2bf(lo.w);
            a[4] = (short)f2bf(hi.x); a[5] = (short)f2bf(hi.y);
            a[6] = (short)f2bf(hi.z); a[7] = (short)f2bf(hi.w);
#pragma unroll
            for (int nt2 = 0; nt2 < 4; ++nt2) {
                int nt = ntBase + nt2;
                bf16x8 bfr = wfv[(nt * 4 + ks) * 64 + lane];
                acc[nt2] = __builtin_amdgcn_mfma_f32_16x16x32_bf16(a, bfr, acc[nt2], 0, 0, 0);
            }
        }

        int rowBase = blockRow + (wv >> 1) * 16;
        int orow_base = rowBase + q * 4;
#pragma unroll
        for (int r = 0; r < 4; ++r) {
            int orow = orow_base + r;
            if (orow < n) {
#pragma unroll
                for (int nt2 = 0; nt2 < 4; ++nt2) {
                    int nt = ntBase + nt2;
                    y[(size_t)orow * DCH + nt * 16 + (lane & 15)] = f2bf(acc[nt2][r]);
                }
            }
        }
    }
}

// ---------------- per-node gather-aggregate + bias + ReLU --------------------
// One wave per node; quarter-wave q handles edge j+q via uint4 loads; per-edge
// source dinv from L2-resident table via fmaf. shfl_xor(16/32) folds quarters.
__global__ __launch_bounds__(256) void k_agg(const uint4* __restrict__ y4,
                                             const int* __restrict__ srow,
                                             const int* __restrict__ off,
                                             const float* __restrict__ dinv,
                                             const float* __restrict__ b,
                                             float* __restrict__ out, int n, int E) {
    int i = blockIdx.x * 4 + (threadIdx.x >> 6);
    if (i >= n) return;
    int lane = threadIdx.x & 63;
    int q = lane >> 4;
    int l16 = lane & 15;
    int s = off[i];
    int e = (i + 1 < n) ? off[i + 1] : E;
    float di = dinv[i];

    float acc[8];
#pragma unroll
    for (int k = 0; k < 8; ++k) acc[k] = 0.f;

    if (q == 0) {   // self-loop: dinv_i * z_i
        uint4 v = y4[(size_t)i * 16 + l16];
        unsigned int p[4] = {v.x, v.y, v.z, v.w};
#pragma unroll
        for (int t = 0; t < 4; ++t) {
            acc[2 * t]     = fmaf(di, __uint_as_float(p[t] << 16), acc[2 * t]);
            acc[2 * t + 1] = fmaf(di, __uint_as_float(p[t] & 0xffff0000u), acc[2 * t + 1]);
        }
    }

    int j = s;
    for (; j + 16 <= e; j += 16) {
        int s0 = srow[j + q];
        int s1 = srow[j + 4 + q];
        int s2 = srow[j + 8 + q];
        int s3 = srow[j + 12 + q];
        float d0 = dinv[s0], d1 = dinv[s1], d2 = dinv[s2], d3 = dinv[s3];
        uint4 v0 = y4[(size_t)s0 * 16 + l16];
        uint4 v1 = y4[(size_t)s1 * 16 + l16];
        uint4 v2 = y4[(size_t)s2 * 16 + l16];
        uint4 v3 = y4[(size_t)s3 * 16 + l16];
        unsigned int p0[4] = {v0.x, v0.y, v0.z, v0.w};
        unsigned int p1[4] = {v1.x, v1.y, v1.z, v1.w};
        unsigned int p2[4] = {v2.x, v2.y, v2.z, v2.w};
        unsigned int p3[4] = {v3.x, v3.y, v3.z, v3.w};
#pragma unroll
        for (int t = 0; t < 4; ++t) {
            acc[2 * t]     = fmaf(d0, __uint_as_float(p0[t] << 16), acc[2 * t]);
            acc[2 * t + 1] = fmaf(d0, __uint_as_float(p0[t] & 0xffff0000u), acc[2 * t + 1]);
            acc[2 * t]     = fmaf(d1, __uint_as_float(p1[t] << 16), acc[2 * t]);
            acc[2 * t + 1] = fmaf(d1, __uint_as_float(p1[t] & 0xffff0000u), acc[2 * t + 1]);
            acc[2 * t]     = fmaf(d2, __uint_as_float(p2[t] << 16), acc[2 * t]);
            acc[2 * t + 1] = fmaf(d2, __uint_as_float(p2[t] & 0xffff0000u), acc[2 * t + 1]);
            acc[2 * t]     = fmaf(d3, __uint_as_float(p3[t] << 16), acc[2 * t]);
            acc[2 * t + 1] = fmaf(d3, __uint_as_float(p3[t] & 0xffff0000u), acc[2 * t + 1]);
        }
    }
    for (; j + 8 <= e; j += 8) {
        int s0 = srow[j + q];
        int s1 = srow[j + 4 + q];
        float d0 = dinv[s0], d1 = dinv[s1];
        uint4 v0 = y4[(size_t)s0 * 16 + l16];
        uint4 v1 = y4[(size_t)s1 * 16 + l16];
        unsigned int p0[4] = {v0.x, v0.y, v0.z, v0.w};
        unsigned int p1[4] = {v1.x, v1.y, v1.z, v1.w};
#pragma unroll
        for (int t = 0; t < 4; ++t) {
            acc[2 * t]     = fmaf(d0, __uint_as_float(p0[t] << 16), acc[2 * t]);
            acc[2 * t + 1] = fmaf(d0, __uint_as_float(p0[t] & 0xffff0000u), acc[2 * t + 1]);
            acc[2 * t]     = fmaf(d1, __uint_as_float(p1[t] << 16), acc[2 * t]);
            acc[2 * t + 1] = fmaf(d1, __uint_as_float(p1[t] & 0xffff0000u), acc[2 * t + 1]);
        }
    }
    for (; j + 4 <= e; j += 4) {
        int s0 = srow[j + q];
        float d0 = dinv[s0];
        uint4 v0 = y4[(size_t)s0 * 16 + l16];
        unsigned int p0[4] = {v0.x, v0.y, v0.z, v0.w};
#pragma unroll
        for (int t = 0; t < 4; ++t) {
            acc[2 * t]     = fmaf(d0, __uint_as_float(p0[t] << 16), acc[2 * t]);
            acc[2 * t + 1] = fmaf(d0, __uint_as_float(p0[t] & 0xffff0000u), acc[2 * t + 1]);
        }
    }
    if (j + q < e) {
        int s0 = srow[j + q];
        float d0 = dinv[s0];
        uint4 v0 = y4[(size_t)s0 * 16 + l16];
        unsigned int p0[4] = {v0.x, v0.y, v0.z, v0.w};
#pragma unroll
        for (int t = 0; t < 4; ++t) {
            acc[2 * t]     = fmaf(d0, __uint_as_float(p0[t] << 16), acc[2 * t]);
            acc[2 * t + 1] = fmaf(d0, __uint_as_float(p0[t] & 0xffff0000u), acc[2 * t + 1]);
        }
    }

#pragma unroll
    for (int k = 0; k < 8; ++k) {
        acc[k] += __shfl_xor(acc[k], 16, 64);
        acc[k] += __shfl_xor(acc[k], 32, 64);
    }

    if (q == 0) {
        float sc = di;
        int c0 = l16 * 8;
        float4 b0 = *(const float4*)&b[c0];
        float4 b1 = *(const float4*)&b[c0 + 4];
        f32x4 o0, o1;
        o0[0] = fmaxf(fmaf(sc, acc[0], b0.x), 0.f);
        o0[1] = fmaxf(fmaf(sc, acc[1], b0.y), 0.f);
        o0[2] = fmaxf(fmaf(sc, acc[2], b0.z), 0.f);
        o0[3] = fmaxf(fmaf(sc, acc[3], b0.w), 0.f);
        o1[0] = fmaxf(fmaf(sc, acc[4], b1.x), 0.f);
        o1[1] = fmaxf(fmaf(sc, acc[5], b1.y), 0.f);
        o1[2] = fmaxf(fmaf(sc, acc[6], b1.z), 0.f);
        o1[3] = fmaxf(fmaf(sc, acc[7], b1.w), 0.f);
        f32x4* orow = (f32x4*)&out[(size_t)i * DCH + c0];
        __builtin_nontemporal_store(o0, &orow[0]);
        __builtin_nontemporal_store(o1, &orow[1]);
    }
}

extern "C" void kernel_launch(void* const* d_in, const int* in_sizes, int n_in,
                              void* d_out, int out_size, void* d_ws, size_t ws_size,
                              hipStream_t stream) {
    const float* x = (const float*)d_in[0];
    const int* ei  = (const int*)d_in[1];
    const float* W = (const float*)d_in[2];
    const float* b = (const float*)d_in[3];
    float* out = (float*)d_out;

    int n = in_sizes[0] / DCH;     // 100000
    int E = in_sizes[1] / 2;       // 1600000
    const int* row = ei;           // sources
    const int* col = ei + E;       // destinations

    int B = (n + 255) / 256;       // 391 node buckets

    char* ws = (char*)d_ws;
    size_t o = 0;
    auto alloc = [&](size_t bytes) -> void* {
        o = (o + 255) & ~(size_t)255;
        void* p = ws + o;
        o += bytes;
        return p;
    };
    int* cnt     = (int*)alloc((size_t)(n + B) * 4);   // cnt[n] + gcount[B], one memset
    int* gcount  = cnt + n;
    float* dinvf = (float*)alloc((size_t)n * 4);
    int* off     = (int*)alloc((size_t)(n + 1) * 4);
    int* cur     = (int*)alloc((size_t)n * 4);
    int* srow    = (int*)alloc((size_t)E * 4);
    unsigned short* Wf = (unsigned short*)alloc((size_t)DCH * DCH * 2);
    unsigned short* y  = (unsigned short*)alloc((size_t)n * DCH * 2);   // 25.6 MB

    int nEB = (E + T_EDGE - 1) / T_EDGE;       // 391 edge blocks
    int gemmBlocks = (n + 63) / 64;            // 1563 gemm blocks

    hipMemsetAsync(cnt, 0, (size_t)(n + B) * 4, stream);
    k_hist<<<nEB + 4, 512, 0, stream>>>(col, cnt, gcount, W, Wf, E, B, nEB);
    k_off<<<B, 512, 0, stream>>>(cnt, gcount, off, cur, dinvf, n, B);
    k_scat<<<nEB + gemmBlocks, 512, 0, stream>>>(row, col, cur, srow,
                                                 x, Wf, y, E, n, nEB);
    k_agg<<<(n + 3) / 4, 256, 0, stream>>>((const uint4*)y, srow, off, dinvf,
                                           b, out, n, E);
}